// Round 11
// baseline (114.009 us; speedup 1.0000x reference)
//
#include <hip/hip_runtime.h>

// Problem constants (fixed by the reference module)
#define B_ 16
#define L_ 2048
#define D_ 128
#define GROUP_ 16
#define NG_ (L_ / GROUP_)   // 128
#define LOG2E_ 1.44269504088896340736f

// DPP-based butterfly add within each 16-lane row (full-rate VALU, no LDS).
template<int CTRL>
__device__ __forceinline__ float dpp_add(float v) {
    int x = __builtin_amdgcn_update_dpp(0, __float_as_int(v), CTRL, 0xF, 0xF, false);
    return v + __int_as_float(x);
}
__device__ __forceinline__ float row16_sum(float v) {
    v = dpp_add<0xB1>(v);   // quad_perm(1,0,3,2)  ~ xor 1
    v = dpp_add<0x4E>(v);   // quad_perm(2,3,0,1)  ~ xor 2
    v = dpp_add<0x141>(v);  // row_half_mirror     ~ xor 4
    v = dpp_add<0x140>(v);  // row_mirror          ~ xor 8
    return v;
}

// lgkm-only barrier (no vmcnt drain on the 16-step critical path).
#define LGKM_BARRIER() asm volatile("s_waitcnt lgkmcnt(0)\n\ts_barrier" ::: "memory")

// R20 = R17 (best with known counters: 44.0us, VALUBusy 57.7, occ 25.4)
// + BLOCK DE-PHASING.
// Corrected pipe model: trans issues on the VALU port at 1/4 rate, so
// busy = VALU(11us) + trans(13.6us) = 25us == measured VALUBusy*dur in
// R9/R17/R18 -> the busy side is at its algorithmic floor; the ENTIRE
// remaining gap is ~18us (40%) stall, invariant across occupancy 17-62%.
// 8 independently-phased blocks/CU stalling simultaneously 40% of the
// time is statistically impossible -> blocks are PHASE-LOCKED (identical
// step durations, simultaneous start): barrier/lgkm stalls and the final
// 33MB scatter-write burst all coincide. Fix: skew block start by
// (blk&7)*768 cyc via s_sleep (sleeping waves free the SIMD; skew
// persists since barriers are block-local). Block k's stall windows are
// then filled by k+-1's compute; the write tail de-bursts into 8 phases.
//
// Per-row elementwise update (identical arithmetic to R14/R17):
#define UPDATE_ROW(CXI, ZA, SIMV, SELFN)                                      \
    _Pragma("unroll")                                                         \
    for (int k = 0; k < 4; ++k) {                                             \
        v2 u  = __builtin_elementwise_fma(SIMV, xjv[k], CXI[k]);              \
        v2 r1 = (v2){__builtin_amdgcn_rcpf(__builtin_amdgcn_exp2f(u.x) + 1.0f),   \
                     __builtin_amdgcn_rcpf(__builtin_amdgcn_exp2f(u.y) + 1.0f)};  \
        v2 tnS = __builtin_elementwise_fma(G1S[k], r1, B1S[k]);               \
        v2 FvS = SELFN(tnS, tnS * leak);                                      \
        ZA[k] += FvS;                                                         \
        v2 r2 = (v2){__builtin_amdgcn_rcpf(__builtin_amdgcn_exp2f(ZA[k].x) + 1.0f), \
                     __builtin_amdgcn_rcpf(__builtin_amdgcn_exp2f(ZA[k].y) + 1.0f)}; \
        CXI[k] = __builtin_elementwise_fma(G2c[k], r2, CXI[k] + B2c[k]);      \
    }

typedef float v2 __attribute__((ext_vector_type(2)));

#define STEP_LOOP(SELFN)                                                      \
    for (int j = 0; j < GROUP_; ++j) {                                        \
        const int p = j & 1;                                                  \
        v2 xjv[4];                                                            \
        {                                                                     \
            float4 tA = *(const float4*)&s_xj[p][d0];                         \
            float4 tB = *(const float4*)&s_xj[p][d0 + 4];                     \
            xjv[0] = (v2){tA.x, tA.y}; xjv[1] = (v2){tA.z, tA.w};             \
            xjv[2] = (v2){tB.x, tB.y}; xjv[3] = (v2){tB.z, tB.w};             \
        }                                                                     \
        /* shared xj-dot partial, then per-row partials */                    \
        v2 pjv = (v2){0.0f, 0.0f};                                            \
        _Pragma("unroll")                                                     \
        for (int k = 0; k < 4; ++k) pjv = __builtin_elementwise_fma(xjv[k], Wj[k], pjv); \
        v2 svA = pjv, svB = pjv;                                              \
        _Pragma("unroll")                                                     \
        for (int k = 0; k < 4; ++k) svA = __builtin_elementwise_fma(cxiA[k], Wi[k], svA); \
        _Pragma("unroll")                                                     \
        for (int k = 0; k < 4; ++k) svB = __builtin_elementwise_fma(cxiB[k], Wi[k], svB); \
        const float simA = row16_sum(svA.x + svA.y);                          \
        const float simB = row16_sum(svB.x + svB.y);                          \
        const v2 simAv = (v2){simA, simA};                                    \
        const v2 simBv = (v2){simB, simB};                                    \
        UPDATE_ROW(cxiA, zaA, simAv, SELFN)                                   \
        UPDATE_ROW(cxiB, zaB, simBv, SELFN)                                   \
        const int jn = j + 1;                                                 \
        if (jn < GROUP_ && rp == (jn & 7)) {                                  \
            if (jn & 8) {                                                     \
                float4 oA = {cxiB[0].x, cxiB[0].y, cxiB[1].x, cxiB[1].y};     \
                float4 oB = {cxiB[2].x, cxiB[2].y, cxiB[3].x, cxiB[3].y};     \
                *(float4*)&s_xj[p ^ 1][d0]     = oA;                          \
                *(float4*)&s_xj[p ^ 1][d0 + 4] = oB;                          \
            } else {                                                          \
                float4 oA = {cxiA[0].x, cxiA[0].y, cxiA[1].x, cxiA[1].y};     \
                float4 oB = {cxiA[2].x, cxiA[2].y, cxiA[3].x, cxiA[3].y};     \
                *(float4*)&s_xj[p ^ 1][d0]     = oA;                          \
                *(float4*)&s_xj[p ^ 1][d0 + 4] = oB;                          \
            }                                                                 \
        }                                                                     \
        LGKM_BARRIER();                                                       \
    }

__global__ __launch_bounds__(128)
__attribute__((amdgpu_waves_per_eu(4, 4)))
void ncn_kernel(
    const float* __restrict__ x,       // (B, L, D)
    const int*   __restrict__ gt,      // (B, L) permutation
    const int*   __restrict__ ctxlens, // (B,)
    const float* __restrict__ W,       // (2D,)
    const float* __restrict__ nalpha,  // (2,)
    const float* __restrict__ ngamma,  // (2D,)
    const float* __restrict__ nbeta,   // (2D,)
    float* __restrict__ out)           // (2, B, L, D) concat: yi_out, ya_out
{
    // ---- de-phase: skew start by (blk&7)*~768 cyc (s_sleep frees the SIMD)
    {
        const int skew = blockIdx.x & 7;
#pragma unroll 1
        for (int i = 0; i < skew; ++i) __builtin_amdgcn_s_sleep(12);
    }

    const int blk = blockIdx.x;
    const int b   = blk >> 7;      // / NG_
    const int g   = blk & (NG_ - 1);
    const int tid = threadIdx.x;   // 0..127
    const int rp  = tid >> 4;      // 0..7 (row pair: owns rows rp and rp+8)
    const int rl  = tid & 15;      // 0..15 (lane within row)
    const int d0  = rl << 3;       // 8 d-elements per thread

    __shared__ float s_xj[2][D_];  // double-buffered broadcast row (holds cxj)

    const float a1 = nalpha[0];
    const float a2 = nalpha[1];
    const float ca = -a1 * LOG2E_;        // u = ca*(xi + sim*xj); ALPHA=0.5 folded
    const float S  = -2.0f * a2 * LOG2E_; // za = S*xa, so exp2(za) direct
    const float inv_ca = 1.0f / ca;
    const bool  selMin = (S < 0.0f);      // leaky-relu under sign flip

    // Per-chunk constants (reused 16x), packed v2. Wi,Wj pre-scaled by
    // 1/ca (sim from cxi); G2c,B2c pre-scaled by ca.
    v2 Wi[4], Wj[4], G1S[4], B1S[4], G2c[4], B2c[4];
    {
        float4 wA = *(const float4*)(W + d0);
        float4 wB = *(const float4*)(W + d0 + 4);
        float4 vA = *(const float4*)(W + D_ + d0);
        float4 vB = *(const float4*)(W + D_ + d0 + 4);
        Wi[0] = inv_ca * (v2){wA.x, wA.y}; Wi[1] = inv_ca * (v2){wA.z, wA.w};
        Wi[2] = inv_ca * (v2){wB.x, wB.y}; Wi[3] = inv_ca * (v2){wB.z, wB.w};
        Wj[0] = inv_ca * (v2){vA.x, vA.y}; Wj[1] = inv_ca * (v2){vA.z, vA.w};
        Wj[2] = inv_ca * (v2){vB.x, vB.y}; Wj[3] = inv_ca * (v2){vB.z, vB.w};

        float4 g1A = *(const float4*)(ngamma + d0);
        float4 g1B = *(const float4*)(ngamma + d0 + 4);
        float4 g2A = *(const float4*)(ngamma + D_ + d0);
        float4 g2B = *(const float4*)(ngamma + D_ + d0 + 4);
        float4 b1A = *(const float4*)(nbeta + d0);
        float4 b1B = *(const float4*)(nbeta + d0 + 4);
        float4 b2A = *(const float4*)(nbeta + D_ + d0);
        float4 b2B = *(const float4*)(nbeta + D_ + d0 + 4);

        v2 g1v[4] = {(v2){g1A.x,g1A.y},(v2){g1A.z,g1A.w},(v2){g1B.x,g1B.y},(v2){g1B.z,g1B.w}};
        v2 b1v[4] = {(v2){b1A.x,b1A.y},(v2){b1A.z,b1A.w},(v2){b1B.x,b1B.y},(v2){b1B.z,b1B.w}};
        v2 g2v[4] = {(v2){g2A.x,g2A.y},(v2){g2A.z,g2A.w},(v2){g2B.x,g2B.y},(v2){g2B.z,g2B.w}};
        v2 b2v[4] = {(v2){b2A.x,b2A.y},(v2){b2A.z,b2A.w},(v2){b2B.x,b2B.y},(v2){b2B.z,b2B.w}};
#pragma unroll
        for (int k = 0; k < 4; ++k) {
            G1S[k] = (S * 2.0f) * g1v[k];        // S*(2*g1)
            B1S[k] = S * (b1v[k] - g1v[k]);      // S*(b1-g1)
            G2c[k] = (ca * 2.0f) * g2v[k];       // ca*(2*g2)
            B2c[k] = ca * (b2v[k] - g2v[k]);     // ca*(b2-g2)
        }
    }

    // Tokens + gather for BOTH owned rows; state is cxi = ca * xi.
    const int lA   = g * GROUP_ + rp;
    const int tokA = gt[b * L_ + lA];
    const int tokB = gt[b * L_ + lA + 8];
    const float* xpA = x + ((size_t)(b * L_ + tokA)) * D_ + d0;
    const float* xpB = x + ((size_t)(b * L_ + tokB)) * D_ + d0;

    v2 cxiA[4], zaA[4], cxiB[4], zaB[4];
    {
        const v2 cav = (v2){ca, ca};
        float4 xA = *(const float4*)xpA;
        float4 xB = *(const float4*)(xpA + 4);
        cxiA[0] = cav * (v2){xA.x, xA.y}; cxiA[1] = cav * (v2){xA.z, xA.w};
        cxiA[2] = cav * (v2){xB.x, xB.y}; cxiA[3] = cav * (v2){xB.z, xB.w};
        float4 yA = *(const float4*)xpB;
        float4 yB = *(const float4*)(xpB + 4);
        cxiB[0] = cav * (v2){yA.x, yA.y}; cxiB[1] = cav * (v2){yA.z, yA.w};
        cxiB[2] = cav * (v2){yB.x, yB.y}; cxiB[3] = cav * (v2){yB.z, yB.w};
    }
#pragma unroll
    for (int k = 0; k < 4; ++k) { zaA[k] = (v2){0.0f, 0.0f}; zaB[k] = (v2){0.0f, 0.0f}; }

    // Row 0 (pair 0, sub-row A) publishes its initial cxi into buffer 0
    if (rp == 0) {
        float4 oA = {cxiA[0].x, cxiA[0].y, cxiA[1].x, cxiA[1].y};
        float4 oB = {cxiA[2].x, cxiA[2].y, cxiA[3].x, cxiA[3].y};
        *(float4*)&s_xj[0][d0]     = oA;
        *(float4*)&s_xj[0][d0 + 4] = oB;
    }
    __syncthreads();

    const v2 leak = (v2){0.01f, 0.01f};

    // Uniform split: one v_pk_min / v_pk_max per elem.
    if (selMin) {
        STEP_LOOP(__builtin_elementwise_min)
    } else {
        STEP_LOOP(__builtin_elementwise_max)
    }

    // Recover xi = cxi / ca and xa = za / S; scatter both rows.
    const float invS = 1.0f / S;
    const v2 invSv  = (v2){invS, invS};
    const v2 invCav = (v2){1.0f / ca, 1.0f / ca};

    const bool valid = (g * GROUP_) < ctxlens[b];

    float* o1A = out + ((size_t)(b * L_ + tokA)) * D_ + d0;
    float* o1B = out + ((size_t)(b * L_ + tokB)) * D_ + d0;
    float* o2A = o1A + (size_t)B_ * L_ * D_;
    float* o2B = o1B + (size_t)B_ * L_ * D_;

    v2 yiA[4], yaA[4], yiB[4], yaB[4];
#pragma unroll
    for (int k = 0; k < 4; ++k) {
        yiA[k] = cxiA[k] * invCav; yaA[k] = zaA[k] * invSv;
        yiB[k] = cxiB[k] * invCav; yaB[k] = zaB[k] * invSv;
    }
    if (!valid) {
#pragma unroll
        for (int k = 0; k < 4; ++k) {
            yiA[k] = (v2){0,0}; yaA[k] = (v2){0,0};
            yiB[k] = (v2){0,0}; yaB[k] = (v2){0,0};
        }
    }

    float4 s1A = {yiA[0].x, yiA[0].y, yiA[1].x, yiA[1].y};
    float4 s1B = {yiA[2].x, yiA[2].y, yiA[3].x, yiA[3].y};
    float4 s2A = {yaA[0].x, yaA[0].y, yaA[1].x, yaA[1].y};
    float4 s2B = {yaA[2].x, yaA[2].y, yaA[3].x, yaA[3].y};
    *(float4*)o1A       = s1A;
    *(float4*)(o1A + 4) = s1B;
    *(float4*)o2A       = s2A;
    *(float4*)(o2A + 4) = s2B;

    float4 t1A = {yiB[0].x, yiB[0].y, yiB[1].x, yiB[1].y};
    float4 t1B = {yiB[2].x, yiB[2].y, yiB[3].x, yiB[3].y};
    float4 t2A = {yaB[0].x, yaB[0].y, yaB[1].x, yaB[1].y};
    float4 t2B = {yaB[2].x, yaB[2].y, yaB[3].x, yaB[3].y};
    *(float4*)o1B       = t1A;
    *(float4*)(o1B + 4) = t1B;
    *(float4*)o2B       = t2A;
    *(float4*)(o2B + 4) = t2B;
}

extern "C" void kernel_launch(void* const* d_in, const int* in_sizes, int n_in,
                              void* d_out, int out_size, void* d_ws, size_t ws_size,
                              hipStream_t stream) {
    const float* x  = (const float*)d_in[0];
    const int*   gt = (const int*)d_in[1];
    const int*   cl = (const int*)d_in[2];
    const float* W  = (const float*)d_in[3];
    const float* na = (const float*)d_in[4];
    const float* ng = (const float*)d_in[5];
    const float* nb = (const float*)d_in[6];
    float* out = (float*)d_out;

    ncn_kernel<<<B_ * NG_, 128, 0, stream>>>(x, gt, cl, W, na, ng, nb, out);
}

// Round 12
// 110.853 us; speedup vs baseline: 1.0285x; 1.0285x over previous
//
#include <hip/hip_runtime.h>

// Problem constants (fixed by the reference module)
#define B_ 16
#define L_ 2048
#define D_ 128
#define GROUP_ 16
#define NG_ (L_ / GROUP_)   // 128
#define LOG2E_ 1.44269504088896340736f

typedef float v2 __attribute__((ext_vector_type(2)));

// DPP-based butterfly add within each 16-lane row (full-rate VALU, no LDS).
template<int CTRL>
__device__ __forceinline__ float dpp_add(float v) {
    int x = __builtin_amdgcn_update_dpp(0, __float_as_int(v), CTRL, 0xF, 0xF, false);
    return v + __int_as_float(x);
}
__device__ __forceinline__ float row16_sum(float v) {
    v = dpp_add<0xB1>(v);   // quad_perm(1,0,3,2)  ~ xor 1
    v = dpp_add<0x4E>(v);   // quad_perm(2,3,0,1)  ~ xor 2
    v = dpp_add<0x141>(v);  // row_half_mirror     ~ xor 4
    v = dpp_add<0x140>(v);  // row_mirror          ~ xor 8
    return v;
}

// lgkm-only barrier (no vmcnt drain on the 16-step critical path).
#define LGKM_BARRIER() asm volatile("s_waitcnt lgkmcnt(0)\n\ts_barrier" ::: "memory")

// R21 = R16 VERBATIM (best measured of the session: harness 111.4us,
// kernel below the 43.6us memset floor). Session conclusion:
//  - Busy side at algorithmic floor: VALU ~11us + trans ~13.6us (trans
//    issues on the VALU port at 1/4 rate) = ~25us == measured
//    VALUBusy*dur in every properly-counted round. No issue left to cut;
//    trans<->VALU trades lose (R11 + corrected pipe model).
//  - Remaining ~18us is serial-recurrence latency (per-step: ds_read ->
//    24-deep dot chain -> 5-stage DPP reduce -> 2 dependent trans chains
//    -> publish -> barrier), invariant across occupancy 17-62%, barrier
//    domain 1/2/4 waves, allocation strategy, scalar/packed form,
//    2-groups/block, and block de-phasing (R20 null). Practical floor.
//
// STEP_LOOP macro: SELFN = min (S<0) or max (S>=0), uniform per launch.
#define STEP_LOOP(SELFN)                                                      \
    for (int j = 0; j < GROUP_; ++j) {                                        \
        const int p = j & 1;                                                  \
        v2 xjv[4];                                                            \
        {                                                                     \
            float4 tA = *(const float4*)&s_xj[p][d0];                         \
            float4 tB = *(const float4*)&s_xj[p][d0 + 4];                     \
            xjv[0] = (v2){tA.x, tA.y}; xjv[1] = (v2){tA.z, tA.w};             \
            xjv[2] = (v2){tB.x, tB.y}; xjv[3] = (v2){tB.z, tB.w};             \
        }                                                                     \
        v2 sv = (v2){0.0f, 0.0f};                                             \
        _Pragma("unroll")                                                     \
        for (int k = 0; k < 4; ++k) sv = __builtin_elementwise_fma(cxi[k], Wi[k], sv); \
        _Pragma("unroll")                                                     \
        for (int k = 0; k < 4; ++k) sv = __builtin_elementwise_fma(xjv[k], Wj[k], sv); \
        const float sim = row16_sum(sv.x + sv.y);                             \
        const v2 simv = (v2){sim, sim};                                       \
        _Pragma("unroll")                                                     \
        for (int k = 0; k < 4; ++k) {                                         \
            v2 u  = __builtin_elementwise_fma(simv, xjv[k], cxi[k]);          \
            v2 r1 = (v2){__builtin_amdgcn_rcpf(__builtin_amdgcn_exp2f(u.x) + 1.0f),   \
                         __builtin_amdgcn_rcpf(__builtin_amdgcn_exp2f(u.y) + 1.0f)};  \
            v2 tnS = __builtin_elementwise_fma(G1S[k], r1, B1S[k]);           \
            v2 FvS = SELFN(tnS, tnS * leak);                                  \
            za[k] += FvS;                                                     \
            v2 r2 = (v2){__builtin_amdgcn_rcpf(__builtin_amdgcn_exp2f(za[k].x) + 1.0f), \
                         __builtin_amdgcn_rcpf(__builtin_amdgcn_exp2f(za[k].y) + 1.0f)}; \
            cxi[k] = __builtin_elementwise_fma(G2c[k], r2, cxi[k] + B2c[k]);  \
        }                                                                     \
        if (j + 1 < GROUP_ && row == j + 1) {                                 \
            float4 oA = {cxi[0].x, cxi[0].y, cxi[1].x, cxi[1].y};             \
            float4 oB = {cxi[2].x, cxi[2].y, cxi[3].x, cxi[3].y};             \
            *(float4*)&s_xj[p ^ 1][d0]     = oA;                              \
            *(float4*)&s_xj[p ^ 1][d0 + 4] = oB;                              \
        }                                                                     \
        LGKM_BARRIER();                                                       \
    }

__global__ __launch_bounds__(256)
__attribute__((amdgpu_waves_per_eu(4, 4)))
void ncn_kernel(
    const float* __restrict__ x,       // (B, L, D)
    const int*   __restrict__ gt,      // (B, L) permutation
    const int*   __restrict__ ctxlens, // (B,)
    const float* __restrict__ W,       // (2D,)
    const float* __restrict__ nalpha,  // (2,)
    const float* __restrict__ ngamma,  // (2D,)
    const float* __restrict__ nbeta,   // (2D,)
    float* __restrict__ out)           // (2, B, L, D) concat: yi_out, ya_out
{
    const int blk = blockIdx.x;
    const int b   = blk >> 7;      // / NG_
    const int g   = blk & (NG_ - 1);
    const int tid = threadIdx.x;
    const int row = tid >> 4;      // 0..15 (token within group)
    const int rl  = tid & 15;      // 0..15 (lane within row)
    const int d0  = rl << 3;       // 8 d-elements per thread

    __shared__ float s_xj[2][D_];  // double-buffered broadcast row (holds cxj)

    const float a1 = nalpha[0];
    const float a2 = nalpha[1];
    const float ca = -a1 * LOG2E_;        // u = ca*(xi + sim*xj); ALPHA=0.5 folded
    const float S  = -2.0f * a2 * LOG2E_; // za = S*xa, so exp2(za) direct
    const float inv_ca = 1.0f / ca;       // (a1 != 0 on this problem's inputs)
    const bool  selMin = (S < 0.0f);      // leaky-relu under sign flip

    // Per-chunk constants in registers (reused 16x), as packed v2 pairs.
    // Wi,Wj pre-scaled by 1/ca so sim = dot(cxi,Wi') + dot(cxj,Wj').
    // G2c,B2c pre-scaled by ca so cxi' = fma(G2c, r2, cxi + B2c).
    v2 Wi[4], Wj[4], G1S[4], B1S[4], G2c[4], B2c[4];
    {
        float4 wA = *(const float4*)(W + d0);
        float4 wB = *(const float4*)(W + d0 + 4);
        float4 vA = *(const float4*)(W + D_ + d0);
        float4 vB = *(const float4*)(W + D_ + d0 + 4);
        Wi[0] = inv_ca * (v2){wA.x, wA.y}; Wi[1] = inv_ca * (v2){wA.z, wA.w};
        Wi[2] = inv_ca * (v2){wB.x, wB.y}; Wi[3] = inv_ca * (v2){wB.z, wB.w};
        Wj[0] = inv_ca * (v2){vA.x, vA.y}; Wj[1] = inv_ca * (v2){vA.z, vA.w};
        Wj[2] = inv_ca * (v2){vB.x, vB.y}; Wj[3] = inv_ca * (v2){vB.z, vB.w};

        float4 g1A = *(const float4*)(ngamma + d0);
        float4 g1B = *(const float4*)(ngamma + d0 + 4);
        float4 g2A = *(const float4*)(ngamma + D_ + d0);
        float4 g2B = *(const float4*)(ngamma + D_ + d0 + 4);
        float4 b1A = *(const float4*)(nbeta + d0);
        float4 b1B = *(const float4*)(nbeta + d0 + 4);
        float4 b2A = *(const float4*)(nbeta + D_ + d0);
        float4 b2B = *(const float4*)(nbeta + D_ + d0 + 4);

        v2 g1v[4] = {(v2){g1A.x,g1A.y},(v2){g1A.z,g1A.w},(v2){g1B.x,g1B.y},(v2){g1B.z,g1B.w}};
        v2 b1v[4] = {(v2){b1A.x,b1A.y},(v2){b1A.z,b1A.w},(v2){b1B.x,b1B.y},(v2){b1B.z,b1B.w}};
        v2 g2v[4] = {(v2){g2A.x,g2A.y},(v2){g2A.z,g2A.w},(v2){g2B.x,g2B.y},(v2){g2B.z,g2B.w}};
        v2 b2v[4] = {(v2){b2A.x,b2A.y},(v2){b2A.z,b2A.w},(v2){b2B.x,b2B.y},(v2){b2B.z,b2B.w}};
#pragma unroll
        for (int k = 0; k < 4; ++k) {
            G1S[k] = (S * 2.0f) * g1v[k];        // S*(2*g1)
            B1S[k] = S * (b1v[k] - g1v[k]);      // S*(b1-g1)
            G2c[k] = (ca * 2.0f) * g2v[k];       // ca*(2*g2)
            B2c[k] = ca * (b2v[k] - g2v[k]);     // ca*(b2-g2)
        }
    }

    // Gather this row's token; state is cxi = ca * xi.
    const int l   = g * GROUP_ + row;
    const int tok = gt[b * L_ + l];
    const float* xp = x + ((size_t)(b * L_ + tok)) * D_ + d0;

    v2 cxi[4], za[4];
    {
        float4 xA = *(const float4*)xp;
        float4 xB = *(const float4*)(xp + 4);
        const v2 cav = (v2){ca, ca};
        cxi[0] = cav * (v2){xA.x, xA.y}; cxi[1] = cav * (v2){xA.z, xA.w};
        cxi[2] = cav * (v2){xB.x, xB.y}; cxi[3] = cav * (v2){xB.z, xB.w};
    }
#pragma unroll
    for (int k = 0; k < 4; ++k) za[k] = (v2){0.0f, 0.0f};

    // Row 0 publishes its initial cxi into buffer 0
    if (row == 0) {
        float4 oA = {cxi[0].x, cxi[0].y, cxi[1].x, cxi[1].y};
        float4 oB = {cxi[2].x, cxi[2].y, cxi[3].x, cxi[3].y};
        *(float4*)&s_xj[0][d0]     = oA;
        *(float4*)&s_xj[0][d0 + 4] = oB;
    }
    __syncthreads();

    const v2 leak = (v2){0.01f, 0.01f};

    // Uniform split: each path pays exactly one v_pk_min / v_pk_max per elem.
    if (selMin) {
        STEP_LOOP(__builtin_elementwise_min)
    } else {
        STEP_LOOP(__builtin_elementwise_max)
    }

    // Recover xi = cxi / ca and xa = za / S.
    const float invS = 1.0f / S;
    const v2 invSv  = (v2){invS, invS};
    const v2 invCav = (v2){inv_ca, inv_ca};
    v2 xi[4], xa[4];
#pragma unroll
    for (int k = 0; k < 4; ++k) {
        xi[k] = cxi[k] * invCav;
        xa[k] = za[k] * invSv;
    }

    const bool valid = (g * GROUP_) < ctxlens[b];
    if (!valid) {
#pragma unroll
        for (int k = 0; k < 4; ++k) { xi[k] = (v2){0,0}; xa[k] = (v2){0,0}; }
    }

    // Scatter back through the permutation (bijective -> every out elem written)
    float* o1 = out + ((size_t)(b * L_ + tok)) * D_ + d0;
    float* o2 = o1 + (size_t)B_ * L_ * D_;
    float4 s1A = {xi[0].x, xi[0].y, xi[1].x, xi[1].y};
    float4 s1B = {xi[2].x, xi[2].y, xi[3].x, xi[3].y};
    float4 s2A = {xa[0].x, xa[0].y, xa[1].x, xa[1].y};
    float4 s2B = {xa[2].x, xa[2].y, xa[3].x, xa[3].y};
    *(float4*)o1       = s1A;
    *(float4*)(o1 + 4) = s1B;
    *(float4*)o2       = s2A;
    *(float4*)(o2 + 4) = s2B;
}

extern "C" void kernel_launch(void* const* d_in, const int* in_sizes, int n_in,
                              void* d_out, int out_size, void* d_ws, size_t ws_size,
                              hipStream_t stream) {
    const float* x  = (const float*)d_in[0];
    const int*   gt = (const int*)d_in[1];
    const int*   cl = (const int*)d_in[2];
    const float* W  = (const float*)d_in[3];
    const float* na = (const float*)d_in[4];
    const float* ng = (const float*)d_in[5];
    const float* nb = (const float*)d_in[6];
    float* out = (float*)d_out;

    ncn_kernel<<<B_ * NG_, 256, 0, stream>>>(x, gt, cl, W, na, ng, nb, out);
}